// Round 12
// baseline (246.983 us; speedup 1.0000x reference)
//
#include <hip/hip_runtime.h>
#include <hip/hip_fp16.h>
#include <float.h>

#define NSEG 4096
#define CAP 2048   // max edges/segment held in LDS (max segment count ~330)

typedef __attribute__((ext_vector_type(8))) _Float16 half8;
typedef __attribute__((ext_vector_type(2))) _Float16 h2v;
typedef __attribute__((ext_vector_type(4))) float f32x4;
typedef __attribute__((address_space(1))) const unsigned int guint;
typedef __attribute__((address_space(3))) unsigned int luint;

// ---- setup: pack W_j / W_i into MFMA fragment order, split fp16 hi/lo ----
// (seg_bounds moved into seg_softmax — each block self-computes its 2 bounds;
// setup is now pack-only and shorter on the critical path to proj)
// Layout (halves): Wpk[which][kt*8+nt][h(0=hi,1=lo)][lane][r]
//   value = W[k][n], k = kt*32 + (l>>4)*8 + r, n = nt*16 + (l&15)
__global__ __launch_bounds__(256) void setup(
    const float* __restrict__ Wj, const float* __restrict__ Wi,
    __half* __restrict__ Wpk) {
  int tid = blockIdx.x * 256 + threadIdx.x;
  for (int idx = tid; idx < 2 * 4 * 8 * 64 * 8; idx += 32 * 256) {
    int r     = idx & 7;
    int l     = (idx >> 3) & 63;
    int nt    = (idx >> 9) & 7;
    int kt    = (idx >> 12) & 3;
    int which = idx >> 14;
    const float* W = which ? Wi : Wj;
    int k = kt * 32 + (l >> 4) * 8 + r;
    int n = nt * 16 + (l & 15);
    float v = W[k * 128 + n];
    __half hi = __float2half(v);                         // RNE
    __half lo = __float2half(v - __half2float(hi));      // exact residual
    size_t base = ((size_t)which * 32 + (size_t)(kt * 8 + nt)) * 1024;
    Wpk[base + l * 8 + r]       = hi;
    Wpk[base + 512 + l * 8 + r] = lo;
  }
}

// ---- projection GEMM on matrix cores: Y = fp16(X @ W (+bias for which==1)) ----
// v7 = v6 + __launch_bounds__(256, 5): 5 blocks/CU x 32 KB LDS = 160 KB
// (exact fit) -> 20 waves/CU (+25% latency-hiding vs v6's 16). Allocator
// pinned to <=102 VGPR/wave (v6 structure estimated ~85-95, should fit
// without spill). Structure and numerics identical to v6 (bitwise Y).
__global__ __launch_bounds__(256, 5) void proj_mfma(
    const float* __restrict__ Xj, const float* __restrict__ Xi,
    const float* __restrict__ bias, const __half* __restrict__ Wpk,
    __half* __restrict__ Yj, __half* __restrict__ Yi, int nrows) {
  const int which = blockIdx.y;
  const float* X = which ? Xi : Xj;
  __half* Y = which ? Yi : Yj;
  const _Float16* WpkB = (const _Float16*)Wpk + (size_t)which * 32768;

  __shared__ _Float16 Wlds[2][8192];   // 2 x 16 KB kt-chunks

  const int tid  = threadIdx.x;
  const int wid  = tid >> 6;
  const int lane = tid & 63;
  const int lr   = lane & 15;   // X row within the wave's 16-row tile
  const int lg   = lane >> 4;   // k-chunk group; D reg-quad selects output cols

  const long row0 = (long)blockIdx.x * 64 + wid * 16;   // wave's 16 rows
  long r0 = row0 + lr;
  const float* p0 = X + (r0 < nrows ? r0 : 0) * 128 + lg * 8;  // clamp: safe read

// stage one 16 KB W chunk into Wlds[buf] via global_load_lds (4 lines/thread;
// per-wave uniform LDS base + lane*16B matches the HW linear-dest semantics)
#define STAGE_CHUNK(buf, chunkIdx)                                            \
  {                                                                           \
    const float4* s_ = (const float4*)(WpkB + (chunkIdx) * 8192);             \
    _Float16* lb_ = (_Float16*)Wlds[buf];                                     \
    _Pragma("unroll")                                                         \
    for (int it_ = 0; it_ < 4; ++it_) {                                       \
      __builtin_amdgcn_global_load_lds(                                       \
          (guint*)(const void*)(s_ + it_ * 256 + tid),                        \
          (luint*)(void*)(lb_ + (it_ * 256 + wid * 64) * 8),                  \
          16, 0, 0);                                                          \
    }                                                                         \
  }

  // ---- prologue: stage W chunk 0 + ALL X (8 independent float4/lane) ----
  STAGE_CHUNK(0, 0)
  float4 xr[8];
  #pragma unroll
  for (int kt = 0; kt < 4; ++kt) {
    xr[2 * kt]     = *(const float4*)(p0 + kt * 32);
    xr[2 * kt + 1] = *(const float4*)(p0 + kt * 32 + 4);
  }

  __syncthreads();   // drains vmcnt: chunk0 in LDS, X rows in regs

  f32x4 acc[8] = {};

#define CVT1(dsth, dstl, idx, val)                                   \
  { float v_ = (val); _Float16 h_ = (_Float16)v_;                    \
    dsth[idx] = h_; dstl[idx] = (_Float16)(v_ - (float)h_); }
#define CVT8(dsth, dstl, v0, v1)                                     \
  CVT1(dsth, dstl, 0, (v0).x) CVT1(dsth, dstl, 1, (v0).y)            \
  CVT1(dsth, dstl, 2, (v0).z) CVT1(dsth, dstl, 3, (v0).w)            \
  CVT1(dsth, dstl, 4, (v1).x) CVT1(dsth, dstl, 5, (v1).y)            \
  CVT1(dsth, dstl, 6, (v1).z) CVT1(dsth, dstl, 7, (v1).w)

#define MFMA(a, b, c) __builtin_amdgcn_mfma_f32_16x16x32_f16((a), (b), (c), 0, 0, 0)

// HASN1: chunk kt+1 exists -> stage it at top (latency hidden under MFMAs),
// barrier at end publishes it (also fences buffer reuse: all waves are past
// their reads of the overwritten buffer before the next step's loads land)
#define KT_STEP(kt, HASN1)                                               \
  {                                                                      \
    if (HASN1) STAGE_CHUNK(((kt) + 1) & 1, (kt) + 1)                     \
    half8 xh, xl;                                                        \
    CVT8(xh, xl, xr[2 * (kt)], xr[2 * (kt) + 1]);                        \
    _Pragma("unroll")                                                    \
    for (int nt = 0; nt < 8; ++nt) {                                     \
      const _Float16* f = &Wlds[(kt) & 1][nt * 1024 + lane * 8];         \
      half8 wh = *(const half8*)(f);                                     \
      half8 wl = *(const half8*)(f + 512);                               \
      acc[nt] = MFMA(wh, xh, acc[nt]);                                   \
      acc[nt] = MFMA(wh, xl, acc[nt]);                                   \
      acc[nt] = MFMA(wl, xh, acc[nt]);                                   \
    }                                                                    \
    if (HASN1) __syncthreads();                                          \
  }

  KT_STEP(0, 1)
  KT_STEP(1, 1)
  KT_STEP(2, 1)
  KT_STEP(3, 0)

#undef KT_STEP
#undef MFMA
#undef CVT8
#undef CVT1
#undef STAGE_CHUNK

  // ---- epilogue: D layout (swapped operands): lane -> row = row0 + lr,
  //      cols = nt*16 + lg*4 + (0..3) -> packed 8B stores ----
  long row = row0 + lr;
  if (row < nrows) {
    __half* yr = Y + row * 128;
    #pragma unroll
    for (int nt = 0; nt < 8; ++nt) {
      float4 bv = make_float4(0.f, 0.f, 0.f, 0.f);
      if (which) bv = *(const float4*)(bias + nt * 16 + lg * 4);
      __half2 v01 = __floats2half2_rn(acc[nt][0] + bv.x, acc[nt][1] + bv.y);
      __half2 v23 = __floats2half2_rn(acc[nt][2] + bv.z, acc[nt][3] + bv.w);
      uint2 u;
      u.x = *(unsigned int*)&v01;
      u.y = *(unsigned int*)&v23;
      *(uint2*)(yr + nt * 16 + lg * 4) = u;
    }
  }
}

// One block per segment. (FROZEN core since R7 — pattern-BW wall: 72-76 us /
// 3.3-3.4 TB/s beyond-L2 invariant across 4 structures.) v5 change: block
// self-computes its 2 segment bounds (2 binary searches, L3-cached, hidden
// across 4096 blocks) — removes the seg_bounds dependency entirely.
__global__ __launch_bounds__(256) void seg_softmax(
    const __half* __restrict__ xjp, const __half* __restrict__ xip,
    const int* __restrict__ ei, const int* __restrict__ batch,
    const float* __restrict__ mlpW, const float* __restrict__ prelu_w,
    const float* __restrict__ mlp_b, float* __restrict__ out, int E) {
  __shared__ int sb[2];
  __shared__ float aS[CAP];
  __shared__ float red[8];

  const int tid = threadIdx.x;
  if (tid < 2) {
    int target = blockIdx.x + tid;
    int lo = 0, hi = E;
    while (lo < hi) { int mid = (lo + hi) >> 1; if (batch[mid] < target) lo = mid + 1; else hi = mid; }
    sb[tid] = lo;
  }
  __syncthreads();
  const int start = sb[0];
  const int end = sb[1];
  const int cnt = end - start;
  if (cnt <= 0) return;

  const int lane = tid & 63;
  const int wid = tid >> 6;
  const int g   = tid >> 4;          // 16 quarter-wave groups per block
  const int ql  = tid & 15;          // lane within group: 8 features x fp16

  const float4 w0 = *(const float4*)(mlpW + ql * 8);
  const float4 w1 = *(const float4*)(mlpW + ql * 8 + 4);
  const float pw = prelu_w[0];
  const float mb = mlp_b[0];
  const bool useLds = (cnt <= CAP);

  const uint4* XJ = (const uint4*)xjp;   // one row = 16 uint4 (256 B)
  const uint4* XI = (const uint4*)xip;
  const h2v pwv = { (_Float16)pw, (_Float16)pw };
  const h2v zv  = { (_Float16)0.f, (_Float16)0.f };

  // ---- phase 1: alpha (4 consecutive edges per group per iteration) ----
  for (int e0 = start + g * 4; e0 < end; e0 += 64) {
    const int eB = e0 + 1, eC = e0 + 2, eD = e0 + 3;
    const bool vB = (eB < end), vC = (eC < end), vD = (eD < end);
    int sA = ei[e0],            dA = ei[E + e0];
    int sB = vB ? ei[eB] : sA,  dB = vB ? ei[E + eB] : dA;
    int sC = vC ? ei[eC] : sA,  dC = vC ? ei[E + eC] : dA;
    int sD = vD ? ei[eD] : sA,  dD = vD ? ei[E + eD] : dA;

    uint4 aA = XJ[(size_t)sA * 16 + ql], bA = XI[(size_t)dA * 16 + ql];
    uint4 aB = XJ[(size_t)sB * 16 + ql], bB = XI[(size_t)dB * 16 + ql];
    uint4 aC = XJ[(size_t)sC * 16 + ql], bC = XI[(size_t)dC * 16 + ql];
    uint4 aD = XJ[(size_t)sD * 16 + ql], bD = XI[(size_t)dD * 16 + ql];

    float pA, pB, pC, pD;
#define EALPHA(av, bv, p)                                                   \
    {                                                                       \
      h2v h0 = *(h2v*)&(av).x + *(h2v*)&(bv).x;                             \
      h2v h1 = *(h2v*)&(av).y + *(h2v*)&(bv).y;                             \
      h2v h2 = *(h2v*)&(av).z + *(h2v*)&(bv).z;                             \
      h2v h3 = *(h2v*)&(av).w + *(h2v*)&(bv).w;                             \
      h0 = __builtin_elementwise_max(h0, zv)                                \
         + pwv * __builtin_elementwise_min(h0, zv);                         \
      h1 = __builtin_elementwise_max(h1, zv)                                \
         + pwv * __builtin_elementwise_min(h1, zv);                         \
      h2 = __builtin_elementwise_max(h2, zv)                                \
         + pwv * __builtin_elementwise_min(h2, zv);                         \
      h3 = __builtin_elementwise_max(h3, zv)                                \
         + pwv * __builtin_elementwise_min(h3, zv);                         \
      p = (float)h0.x * w0.x;                                               \
      p = fmaf((float)h0.y, w0.y, p); p = fmaf((float)h1.x, w0.z, p);       \
      p = fmaf((float)h1.y, w0.w, p); p = fmaf((float)h2.x, w1.x, p);       \
      p = fmaf((float)h2.y, w1.y, p); p = fmaf((float)h3.x, w1.z, p);       \
      p = fmaf((float)h3.y, w1.w, p);                                       \
    }
    EALPHA(aA, bA, pA);
    EALPHA(aB, bB, pB);
    EALPHA(aC, bC, pC);
    EALPHA(aD, bD, pD);
#undef EALPHA

    #pragma unroll
    for (int off = 1; off < 16; off <<= 1) {
      pA += __shfl_xor(pA, off, 64);
      pB += __shfl_xor(pB, off, 64);
      pC += __shfl_xor(pC, off, 64);
      pD += __shfl_xor(pD, off, 64);
    }
    if (ql == 0) {
      if (useLds) {
        aS[e0 - start] = pA + mb;
        if (vB) aS[eB - start] = pB + mb;
        if (vC) aS[eC - start] = pC + mb;
        if (vD) aS[eD - start] = pD + mb;
      } else {
        out[e0] = pA + mb;
        if (vB) out[eB] = pB + mb;
        if (vC) out[eC] = pC + mb;
        if (vD) out[eD] = pD + mb;
      }
    }
  }
  __syncthreads();

  // ---- phase 2: block max ----
  float m = -FLT_MAX;
  if (useLds) { for (int i = tid; i < cnt; i += 256) m = fmaxf(m, aS[i]); }
  else        { for (int i = tid; i < cnt; i += 256) m = fmaxf(m, out[start + i]); }
  #pragma unroll
  for (int off = 1; off < 64; off <<= 1) m = fmaxf(m, __shfl_xor(m, off, 64));
  if (lane == 0) red[wid] = m;
  __syncthreads();
  m = fmaxf(fmaxf(red[0], red[1]), fmaxf(red[2], red[3]));

  // ---- phase 3: exp + block sum ----
  float s = 0.f;
  if (useLds) {
    for (int i = tid; i < cnt; i += 256) { float x = expf(aS[i] - m); aS[i] = x; s += x; }
  } else {
    for (int i = tid; i < cnt; i += 256) { float x = expf(out[start + i] - m); out[start + i] = x; s += x; }
  }
  #pragma unroll
  for (int off = 1; off < 64; off <<= 1) s += __shfl_xor(s, off, 64);
  if (lane == 0) red[4 + wid] = s;
  __syncthreads();
  s = (red[4] + red[5]) + (red[6] + red[7]);

  // ---- phase 4: normalize + write ----
  const float inv = 1.0f / (s + 1e-16f);
  if (useLds) { for (int i = tid; i < cnt; i += 256) out[start + i] = aS[i] * inv; }
  else        { for (int i = tid; i < cnt; i += 256) out[start + i] *= inv; }
}

extern "C" void kernel_launch(void* const* d_in, const int* in_sizes, int n_in,
                              void* d_out, int out_size, void* d_ws, size_t ws_size,
                              hipStream_t stream) {
  const float* x_j      = (const float*)d_in[0];
  const float* x_i      = (const float*)d_in[1];
  const int*   edge_idx = (const int*)d_in[2];
  const int*   batch    = (const int*)d_in[3];
  const float* w_j      = (const float*)d_in[4];
  const float* w_i      = (const float*)d_in[5];
  const float* bias     = (const float*)d_in[6];
  const float* prelu_w  = (const float*)d_in[7];
  const float* mlp_W    = (const float*)d_in[8];
  const float* mlp_b    = (const float*)d_in[9];
  const int nnodes = in_sizes[0] / 128;
  const int E = in_sizes[3];

  __half* Wpk = (__half*)d_ws;                    // 65536 halves = 128 KB
  __half* xjp = Wpk + 65536;
  __half* xip = xjp + (size_t)nnodes * 128;

  hipLaunchKernelGGL(setup, dim3(32), dim3(256), 0, stream, w_j, w_i, Wpk);

  int gblocks = (nnodes + 63) / 64;
  hipLaunchKernelGGL(proj_mfma, dim3(gblocks, 2), dim3(256), 0, stream,
                     x_j, x_i, bias, Wpk, xjp, xip, nnodes);

  hipLaunchKernelGGL(seg_softmax, dim3(NSEG), dim3(256), 0, stream,
                     xjp, xip, edge_idx, batch, mlp_W, prelu_w, mlp_b,
                     (float*)d_out, E);
}